// Round 8
// baseline (151.488 us; speedup 1.0000x reference)
//
#include <hip/hip_runtime.h>

typedef _Float16 f16;
typedef f16 f16x4 __attribute__((ext_vector_type(4)));
typedef f16 f16x8 __attribute__((ext_vector_type(8)));
typedef float f32x4 __attribute__((ext_vector_type(4)));

// state_embed (256,512) f32 | action_feats (256,1000,64) f32 | W1 (576,256) | b1 (256)
// W2 (256,128) | b2 (128) | W3 (128,1) | b3 (1)  -> out (256,1000) f32

#define AF_STRIDE 72    // 64+8 f16 = 36 dwords/row (36%32=4): b128 patterns 2-way (free)
#define H1_STRIDE 264   // 256+8 f16 = 132 dwords/row (132%32=4): 2-way (free)

// ---------- prep: pack W1a^T (A-frag), W2 (B-frag), compute h_state ----------
// A-frag (16x16x32): lane L holds A[m=L&15][k=(L>>4)*8+j], j=0..7
// B-frag:            lane L holds B[k=(L>>4)*8+j][n=L&15]
__global__ __launch_bounds__(256) void prep_kernel(const float* __restrict__ W1,
                                                   const float* __restrict__ W2,
                                                   const float* __restrict__ state,
                                                   const float* __restrict__ b1,
                                                   f16* __restrict__ pw1at,
                                                   f16* __restrict__ pw2,
                                                   float* __restrict__ hstate) {
    __shared__ float srow[512];
    int blk = blockIdx.x;
    int tid = threadIdx.x;
    if (blk < 24) {
        int idx = blk * 256 + tid;              // 0..6143
        int F = idx >> 6;                       // fragment id 0..95
        int L = idx & 63;
        int q = L >> 4, c = L & 15;
        f16x8 v;
        if (F < 32) {                           // pw1at: M=256h (mt 0..15), K=64f (kt 0..1)
            int mt = F >> 1, kt = F & 1;
            #pragma unroll
            for (int j = 0; j < 8; ++j) {
                int f = kt * 32 + q * 8 + j;
                v[j] = (f16)W1[(size_t)(512 + f) * 256 + mt * 16 + c];
            }
            *(f16x8*)(pw1at + ((size_t)F * 64 + L) * 8) = v;
        } else {                                // pw2: K=256 (kt 0..7), N=128 (nt 0..7)
            int F2 = F - 32;
            int nt = F2 >> 3, kt = F2 & 7;
            #pragma unroll
            for (int j = 0; j < 8; ++j) {
                int k = kt * 32 + q * 8 + j;
                v[j] = (f16)W2[(size_t)k * 128 + nt * 16 + c];
            }
            *(f16x8*)(pw2 + ((size_t)F2 * 64 + L) * 8) = v;
        }
    } else {
        int b = blk - 24;                       // one batch row per block (fp32 exact)
        srow[tid] = state[(size_t)b * 512 + tid];
        srow[tid + 256] = state[(size_t)b * 512 + 256 + tid];
        __syncthreads();
        float a0 = 0.f, a1 = 0.f;
        #pragma unroll 8
        for (int f = 0; f < 512; f += 2) {
            a0 = fmaf(srow[f],     W1[(size_t)f * 256 + tid],       a0);
            a1 = fmaf(srow[f + 1], W1[(size_t)(f + 1) * 256 + tid], a1);
        }
        hstate[(size_t)b * 256 + tid] = a0 + a1 + b1[tid];
    }
}

// ---------- fused MLP: 2 tiles x 64 actions/block, h-split waves ----------
// Register budget is the occupancy limiter (VGPR+AGPR unified on gfx950):
// R6 held ~208 regs (W1a 32 + W2 64 + acc1 64 + acc2 32 + misc) -> 2 waves/SIMD.
// Here: W2 streamed from L2 per kt (-64), GEMM1 interleaved with epilogue so
// acc1 live = 16 (-48) -> ~130-160 peak -> 3 waves/SIMD under (256,3) w/o spill.
__global__ __launch_bounds__(256, 3) void fused_kernel(const float* __restrict__ afeat,
                                                       const float* __restrict__ hstate,
                                                       const f16* __restrict__ pw1at,
                                                       const f16* __restrict__ pw2,
                                                       const float* __restrict__ b2,
                                                       const float* __restrict__ W3,
                                                       const float* __restrict__ b3,
                                                       float* __restrict__ out) {
    __shared__ f16 afs2[128 * AF_STRIDE];   // 18432 B — 2 tiles of action_feats (f16)
    __shared__ f16 h1s[64 * H1_STRIDE];     // 33792 B  => 52224 B total -> 3 blocks/CU
    // lds3 aliases afs2's first 1536 B: those rows (0..10) are consumed by GEMM1 t=0
    // before the first lds3 write (post-B1); t=1 reads rows 64..127 only.
    float* lds3 = (float*)afs2;             // 64*6 floats

    int tid = threadIdx.x;
    int w = tid >> 6;                 // wave 0..3
    int L = tid & 63;
    int q = L >> 4, c = L & 15;
    int r0g = blockIdx.x * 128;       // first global action row of this block's 2 tiles

    // ---- resident W1a^T A-frags (32 VGPRs), wave's h-slice [64w, 64w+64) ----
    f16x8 a1f[4][2];
    #pragma unroll
    for (int i = 0; i < 4; ++i)
        #pragma unroll
        for (int kt = 0; kt < 2; ++kt)
            a1f[i][kt] = *(const f16x8*)(pw1at + ((size_t)((4 * w + i) * 2 + kt) * 64 + L) * 8);

    // ---- stage both tiles: 128 rows x 64 f32 -> f16 LDS (b128 writes, 2-way free) ----
    #pragma unroll
    for (int i = 0; i < 4; ++i) {
        int id = i * 256 + tid;               // 32B-chunk id 0..1023
        int row = id >> 3, c32 = id & 7;
        const float* p = afeat + (size_t)(r0g + row) * 64 + c32 * 8;
        f32x4 lo = *(const f32x4*)p;
        f32x4 hi = *(const f32x4*)(p + 4);
        f16x8 v;
        v[0] = (f16)lo[0]; v[1] = (f16)lo[1]; v[2] = (f16)lo[2]; v[3] = (f16)lo[3];
        v[4] = (f16)hi[0]; v[5] = (f16)hi[1]; v[6] = (f16)hi[2]; v[7] = (f16)hi[3];
        *(f16x8*)(afs2 + row * AF_STRIDE + c32 * 8) = v;
    }

    float b3v = b3[0];
    float b2v[2], w3v[2];
    #pragma unroll
    for (int ntl = 0; ntl < 2; ++ntl) {
        int col = (w * 2 + ntl) * 16 + c;
        b2v[ntl] = b2[col];
        w3v[ntl] = W3[col];
    }
    __syncthreads();

    for (int t = 0; t < 2; ++t) {
        int r0 = r0g + t * 64;
        int b0i = r0 / 1000;
        int boundary = (b0i + 1) * 1000;
        int b1i = b0i < 255 ? b0i + 1 : 255;

        // ---- GEMM1 B-frags (shared across i-slices) ----
        f16x8 bf[4][2];
        #pragma unroll
        for (int nt = 0; nt < 4; ++nt)
            #pragma unroll
            for (int kt = 0; kt < 2; ++kt)
                bf[nt][kt] = *(const f16x8*)(afs2 + (t * 64 + nt * 16 + c) * AF_STRIDE + kt * 32 + q * 8);

        // ---- GEMM1 interleaved with epilogue-1: acc1 live = 16 regs per i-slice ----
        #pragma unroll
        for (int i = 0; i < 4; ++i) {
            f32x4 acc[4];
            #pragma unroll
            for (int nt = 0; nt < 4; ++nt) {
                acc[nt] = (f32x4){0.f, 0.f, 0.f, 0.f};
                #pragma unroll
                for (int kt = 0; kt < 2; ++kt)
                    acc[nt] = __builtin_amdgcn_mfma_f32_16x16x32_f16(
                        a1f[i][kt], bf[nt][kt], acc[nt], 0, 0, 0);
            }
            int hbase = (4 * w + i) * 16 + q * 4;
            f32x4 hsA = *(const f32x4*)(hstate + (size_t)b0i * 256 + hbase);
            f32x4 hsB = *(const f32x4*)(hstate + (size_t)b1i * 256 + hbase);
            #pragma unroll
            for (int nt = 0; nt < 4; ++nt) {
                bool sel = (r0 + nt * 16 + c) >= boundary;
                f16x4 hv;
                #pragma unroll
                for (int reg = 0; reg < 4; ++reg) {
                    float v = acc[nt][reg] + (sel ? hsB[reg] : hsA[reg]);
                    v = v > 0.f ? v : 0.f;
                    hv[reg] = (f16)v;
                }
                *(f16x4*)(h1s + (nt * 16 + c) * H1_STRIDE + hbase) = hv;
            }
        }
        __syncthreads();   // B1: h1s ready

        // ---- GEMM2: h2(64x128) = h1 @ W2; wave w owns n-slice [32w, 32w+32);
        //      W2 B-frags streamed from L2 each kt (not VGPR-resident) ----
        f32x4 acc2[4][2];
        #pragma unroll
        for (int rb = 0; rb < 4; ++rb) {
            acc2[rb][0] = (f32x4){0.f, 0.f, 0.f, 0.f};
            acc2[rb][1] = (f32x4){0.f, 0.f, 0.f, 0.f};
        }
        #pragma unroll
        for (int kt = 0; kt < 8; ++kt) {
            f16x8 a2[4];
            #pragma unroll
            for (int rb = 0; rb < 4; ++rb)
                a2[rb] = *(const f16x8*)(h1s + (rb * 16 + c) * H1_STRIDE + kt * 32 + q * 8);
            #pragma unroll
            for (int ntl = 0; ntl < 2; ++ntl) {
                f16x8 bfr = *(const f16x8*)(pw2 + ((size_t)((w * 2 + ntl) * 8 + kt) * 64 + L) * 8);
                #pragma unroll
                for (int rb = 0; rb < 4; ++rb)
                    acc2[rb][ntl] = __builtin_amdgcn_mfma_f32_16x16x32_f16(
                        a2[rb], bfr, acc2[rb][ntl], 0, 0, 0);
            }
        }

        // ---- layer 3: partial over wave's n-slice; butterfly-reduce over 16 c-lanes ----
        float p[16];
        #pragma unroll
        for (int rb = 0; rb < 4; ++rb)
            #pragma unroll
            for (int reg = 0; reg < 4; ++reg) {
                float v0 = acc2[rb][0][reg] + b2v[0]; v0 = v0 > 0.f ? v0 : 0.f;
                float v1 = acc2[rb][1][reg] + b2v[1]; v1 = v1 > 0.f ? v1 : 0.f;
                p[rb * 4 + reg] = fmaf(v0, w3v[0], v1 * w3v[1]);
            }
        float s0[8];
        #pragma unroll
        for (int i = 0; i < 8; ++i) {
            float send = (c & 1) ? p[2 * i] : p[2 * i + 1];
            float keep = (c & 1) ? p[2 * i + 1] : p[2 * i];
            s0[i] = keep + __shfl_xor(send, 1);
        }
        float s1[4];
        #pragma unroll
        for (int i = 0; i < 4; ++i) {
            float send = (c & 2) ? s0[2 * i] : s0[2 * i + 1];
            float keep = (c & 2) ? s0[2 * i + 1] : s0[2 * i];
            s1[i] = keep + __shfl_xor(send, 2);
        }
        float s2[2];
        #pragma unroll
        for (int i = 0; i < 2; ++i) {
            float send = (c & 4) ? s1[2 * i] : s1[2 * i + 1];
            float keep = (c & 4) ? s1[2 * i + 1] : s1[2 * i];
            s2[i] = keep + __shfl_xor(send, 4);
        }
        float send3 = (c & 8) ? s2[0] : s2[1];
        float keep3 = (c & 8) ? s2[1] : s2[0];
        float s3 = keep3 + __shfl_xor(send3, 8);    // full c-sum for j=c
        int m = (c >> 2) * 16 + q * 4 + (c & 3);
        lds3[m * 6 + w] = s3;
        __syncthreads();   // B2: lds3 ready, h1s consumed

        if (tid < 64) {
            const float* pm = lds3 + tid * 6;
            out[r0 + tid] = pm[0] + pm[1] + pm[2] + pm[3] + b3v;
        }
        __syncthreads();   // B3: lds3 (aliasing afs2) consumed before next t writes
    }
}

extern "C" void kernel_launch(void* const* d_in, const int* in_sizes, int n_in,
                              void* d_out, int out_size, void* d_ws, size_t ws_size,
                              hipStream_t stream) {
    const float* state = (const float*)d_in[0];
    const float* afeat = (const float*)d_in[1];
    const float* W1    = (const float*)d_in[2];
    const float* b1    = (const float*)d_in[3];
    const float* W2    = (const float*)d_in[4];
    const float* b2    = (const float*)d_in[5];
    const float* W3    = (const float*)d_in[6];
    const float* b3    = (const float*)d_in[7];
    float* out = (float*)d_out;

    // ws: hstate 256KB | pw1at 32KB (16384 f16) | pw2 64KB (32768 f16)
    float* hstate = (float*)d_ws;
    f16* pw1at = (f16*)((char*)d_ws + 65536 * sizeof(float));
    f16* pw2   = pw1at + 16384;

    prep_kernel<<<280, 256, 0, stream>>>(W1, W2, state, b1, pw1at, pw2, hstate);
    fused_kernel<<<2000, 256, 0, stream>>>(afeat, hstate, pw1at, pw2, b2, W3, b3, out);
}

// Round 9
// 139.498 us; speedup vs baseline: 1.0860x; 1.0860x over previous
//
#include <hip/hip_runtime.h>

typedef _Float16 f16;
typedef f16 f16x4 __attribute__((ext_vector_type(4)));
typedef f16 f16x8 __attribute__((ext_vector_type(8)));
typedef float f32x4 __attribute__((ext_vector_type(4)));

// state_embed (256,512) f32 | action_feats (256,1000,64) f32 | W1 (576,256) | b1 (256)
// W2 (256,128) | b2 (128) | W3 (128,1) | b3 (1)  -> out (256,1000) f32

#define AF_STRIDE 72    // 64+8 f16 = 36 dwords/row
#define H1_STRIDE 264   // 256+8 f16 = 132 dwords/row

// ---------- prep: pack W1a^T (A-frag), W2 (B-frag), compute h_state ----------
// A-frag (16x16x32): lane L holds A[m=L&15][k=(L>>4)*8+j], j=0..7
// B-frag:            lane L holds B[k=(L>>4)*8+j][n=L&15]
__global__ __launch_bounds__(256) void prep_kernel(const float* __restrict__ W1,
                                                   const float* __restrict__ W2,
                                                   const float* __restrict__ state,
                                                   const float* __restrict__ b1,
                                                   f16* __restrict__ pw1at,
                                                   f16* __restrict__ pw2,
                                                   float* __restrict__ hstate) {
    __shared__ float srow[512];
    int blk = blockIdx.x;
    int tid = threadIdx.x;
    if (blk < 24) {
        int idx = blk * 256 + tid;              // 0..6143
        int F = idx >> 6;                       // fragment id 0..95
        int L = idx & 63;
        int q = L >> 4, c = L & 15;
        f16x8 v;
        if (F < 32) {                           // pw1at: M=256h (mt 0..15), K=64f (kt 0..1)
            int mt = F >> 1, kt = F & 1;
            #pragma unroll
            for (int j = 0; j < 8; ++j) {
                int f = kt * 32 + q * 8 + j;
                v[j] = (f16)W1[(size_t)(512 + f) * 256 + mt * 16 + c];
            }
            *(f16x8*)(pw1at + ((size_t)F * 64 + L) * 8) = v;
        } else {                                // pw2: K=256 (kt 0..7), N=128 (nt 0..7)
            int F2 = F - 32;
            int nt = F2 >> 3, kt = F2 & 7;
            #pragma unroll
            for (int j = 0; j < 8; ++j) {
                int k = kt * 32 + q * 8 + j;
                v[j] = (f16)W2[(size_t)k * 128 + nt * 16 + c];
            }
            *(f16x8*)(pw2 + ((size_t)F2 * 64 + L) * 8) = v;
        }
    } else {
        int b = blk - 24;                       // one batch row per block (fp32 exact)
        srow[tid] = state[(size_t)b * 512 + tid];
        srow[tid + 256] = state[(size_t)b * 512 + 256 + tid];
        __syncthreads();
        float a0 = 0.f, a1 = 0.f;
        #pragma unroll 8
        for (int f = 0; f < 512; f += 2) {
            a0 = fmaf(srow[f],     W1[(size_t)f * 256 + tid],       a0);
            a1 = fmaf(srow[f + 1], W1[(size_t)(f + 1) * 256 + tid], a1);
        }
        hstate[(size_t)b * 256 + tid] = a0 + a1 + b1[tid];
    }
}

// ---------- fused MLP: 2 tiles x 64 actions/block, h-split waves ----------
// Register history: R6 resident-everything = ~208 regs -> 2 waves/SIMD, 43.2us.
// R5/R7: capping to 3 waves (launch_bounds .,3) spills (WRITE_SIZE 95/30 MB).
// This round: low-pressure body (acc1 live=16 via i-slice interleave, W2 streamed
// from L2 per kt) under (256,2) — no cap, no spill; if allocator lands <=170 total
// (VGPR+AGPR unified) the HW gives 3 blocks/CU since LDS 53.76KB <= 54.6KB.
__global__ __launch_bounds__(256, 2) void fused_kernel(const float* __restrict__ afeat,
                                                       const float* __restrict__ hstate,
                                                       const f16* __restrict__ pw1at,
                                                       const f16* __restrict__ pw2,
                                                       const float* __restrict__ b2,
                                                       const float* __restrict__ W3,
                                                       const float* __restrict__ b3,
                                                       float* __restrict__ out) {
    __shared__ f16 afs2[128 * AF_STRIDE];   // 18432 B — 2 tiles of action_feats (f16)
    __shared__ f16 h1s[64 * H1_STRIDE];     // 33792 B
    __shared__ float lds3[2][64 * 6];       //  3072 B (double-buffered per tile -> no B3)
                                            //  total 55296 B... (see note below)

    int tid = threadIdx.x;
    int w = tid >> 6;                 // wave 0..3
    int L = tid & 63;
    int q = L >> 4, c = L & 15;
    int r0g = blockIdx.x * 128;       // first global action row of this block's 2 tiles

    // ---- resident W1a^T A-frags (32 VGPRs), wave's h-slice [64w, 64w+64) ----
    f16x8 a1f[4][2];
    #pragma unroll
    for (int i = 0; i < 4; ++i)
        #pragma unroll
        for (int kt = 0; kt < 2; ++kt)
            a1f[i][kt] = *(const f16x8*)(pw1at + ((size_t)((4 * w + i) * 2 + kt) * 64 + L) * 8);

    // ---- stage both tiles: 128 rows x 64 f32 -> f16 LDS ----
    #pragma unroll
    for (int i = 0; i < 4; ++i) {
        int id = i * 256 + tid;               // 32B-chunk id 0..1023
        int row = id >> 3, c32 = id & 7;
        const float* p = afeat + (size_t)(r0g + row) * 64 + c32 * 8;
        f32x4 lo = *(const f32x4*)p;
        f32x4 hi = *(const f32x4*)(p + 4);
        f16x8 v;
        v[0] = (f16)lo[0]; v[1] = (f16)lo[1]; v[2] = (f16)lo[2]; v[3] = (f16)lo[3];
        v[4] = (f16)hi[0]; v[5] = (f16)hi[1]; v[6] = (f16)hi[2]; v[7] = (f16)hi[3];
        *(f16x8*)(afs2 + row * AF_STRIDE + c32 * 8) = v;
    }

    float b3v = b3[0];
    float b2v[2], w3v[2];
    #pragma unroll
    for (int ntl = 0; ntl < 2; ++ntl) {
        int col = (w * 2 + ntl) * 16 + c;
        b2v[ntl] = b2[col];
        w3v[ntl] = W3[col];
    }
    __syncthreads();

    for (int t = 0; t < 2; ++t) {
        int r0 = r0g + t * 64;
        int b0i = r0 / 1000;
        int boundary = (b0i + 1) * 1000;
        int b1i = b0i < 255 ? b0i + 1 : 255;

        // ---- GEMM1 B-frags (shared across i-slices) ----
        f16x8 bf[4][2];
        #pragma unroll
        for (int nt = 0; nt < 4; ++nt)
            #pragma unroll
            for (int kt = 0; kt < 2; ++kt)
                bf[nt][kt] = *(const f16x8*)(afs2 + (t * 64 + nt * 16 + c) * AF_STRIDE + kt * 32 + q * 8);

        // ---- GEMM1 interleaved with epilogue-1: acc live = 16 regs per i-slice ----
        #pragma unroll
        for (int i = 0; i < 4; ++i) {
            f32x4 acc[4];
            #pragma unroll
            for (int nt = 0; nt < 4; ++nt) {
                acc[nt] = (f32x4){0.f, 0.f, 0.f, 0.f};
                #pragma unroll
                for (int kt = 0; kt < 2; ++kt)
                    acc[nt] = __builtin_amdgcn_mfma_f32_16x16x32_f16(
                        a1f[i][kt], bf[nt][kt], acc[nt], 0, 0, 0);
            }
            int hbase = (4 * w + i) * 16 + q * 4;
            f32x4 hsA = *(const f32x4*)(hstate + (size_t)b0i * 256 + hbase);
            f32x4 hsB = *(const f32x4*)(hstate + (size_t)b1i * 256 + hbase);
            #pragma unroll
            for (int nt = 0; nt < 4; ++nt) {
                bool sel = (r0 + nt * 16 + c) >= boundary;
                f16x4 hv;
                #pragma unroll
                for (int reg = 0; reg < 4; ++reg) {
                    float v = acc[nt][reg] + (sel ? hsB[reg] : hsA[reg]);
                    v = v > 0.f ? v : 0.f;
                    hv[reg] = (f16)v;
                }
                *(f16x4*)(h1s + (nt * 16 + c) * H1_STRIDE + hbase) = hv;
            }
        }
        __syncthreads();   // B1: h1s ready

        // ---- GEMM2: h2(64x128) = h1 @ W2; wave w owns n-slice [32w, 32w+32);
        //      W2 B-frags streamed from L2 each kt (16 KB/wave/tile) ----
        f32x4 acc2[4][2];
        #pragma unroll
        for (int rb = 0; rb < 4; ++rb) {
            acc2[rb][0] = (f32x4){0.f, 0.f, 0.f, 0.f};
            acc2[rb][1] = (f32x4){0.f, 0.f, 0.f, 0.f};
        }
        #pragma unroll
        for (int kt = 0; kt < 8; ++kt) {
            f16x8 a2[4];
            #pragma unroll
            for (int rb = 0; rb < 4; ++rb)
                a2[rb] = *(const f16x8*)(h1s + (rb * 16 + c) * H1_STRIDE + kt * 32 + q * 8);
            #pragma unroll
            for (int ntl = 0; ntl < 2; ++ntl) {
                f16x8 bfr = *(const f16x8*)(pw2 + ((size_t)((w * 2 + ntl) * 8 + kt) * 64 + L) * 8);
                #pragma unroll
                for (int rb = 0; rb < 4; ++rb)
                    acc2[rb][ntl] = __builtin_amdgcn_mfma_f32_16x16x32_f16(
                        a2[rb], bfr, acc2[rb][ntl], 0, 0, 0);
            }
        }

        // ---- layer 3: partial over wave's n-slice; butterfly-reduce over 16 c-lanes ----
        float p[16];
        #pragma unroll
        for (int rb = 0; rb < 4; ++rb)
            #pragma unroll
            for (int reg = 0; reg < 4; ++reg) {
                float v0 = acc2[rb][0][reg] + b2v[0]; v0 = v0 > 0.f ? v0 : 0.f;
                float v1 = acc2[rb][1][reg] + b2v[1]; v1 = v1 > 0.f ? v1 : 0.f;
                p[rb * 4 + reg] = fmaf(v0, w3v[0], v1 * w3v[1]);
            }
        float s0[8];
        #pragma unroll
        for (int i = 0; i < 8; ++i) {
            float send = (c & 1) ? p[2 * i] : p[2 * i + 1];
            float keep = (c & 1) ? p[2 * i + 1] : p[2 * i];
            s0[i] = keep + __shfl_xor(send, 1);
        }
        float s1[4];
        #pragma unroll
        for (int i = 0; i < 4; ++i) {
            float send = (c & 2) ? s0[2 * i] : s0[2 * i + 1];
            float keep = (c & 2) ? s0[2 * i + 1] : s0[2 * i];
            s1[i] = keep + __shfl_xor(send, 2);
        }
        float s2[2];
        #pragma unroll
        for (int i = 0; i < 2; ++i) {
            float send = (c & 4) ? s1[2 * i] : s1[2 * i + 1];
            float keep = (c & 4) ? s1[2 * i + 1] : s1[2 * i];
            s2[i] = keep + __shfl_xor(send, 4);
        }
        float send3 = (c & 8) ? s2[0] : s2[1];
        float keep3 = (c & 8) ? s2[1] : s2[0];
        float s3 = keep3 + __shfl_xor(send3, 8);    // full c-sum for j=c
        int m = (c >> 2) * 16 + q * 4 + (c & 3);
        lds3[t][m * 6 + w] = s3;
        __syncthreads();   // B2: lds3[t] ready, h1s reads done (t=1 GEMM1 may overwrite)

        if (tid < 64) {
            const float* pm = lds3[t] + tid * 6;
            out[r0 + tid] = pm[0] + pm[1] + pm[2] + pm[3] + b3v;
        }
        // no B3: next tile writes lds3[t^1] and h1s (already synced at B2)
    }
}

extern "C" void kernel_launch(void* const* d_in, const int* in_sizes, int n_in,
                              void* d_out, int out_size, void* d_ws, size_t ws_size,
                              hipStream_t stream) {
    const float* state = (const float*)d_in[0];
    const float* afeat = (const float*)d_in[1];
    const float* W1    = (const float*)d_in[2];
    const float* b1    = (const float*)d_in[3];
    const float* W2    = (const float*)d_in[4];
    const float* b2    = (const float*)d_in[5];
    const float* W3    = (const float*)d_in[6];
    const float* b3    = (const float*)d_in[7];
    float* out = (float*)d_out;

    // ws: hstate 256KB | pw1at 32KB (16384 f16) | pw2 64KB (32768 f16)
    float* hstate = (float*)d_ws;
    f16* pw1at = (f16*)((char*)d_ws + 65536 * sizeof(float));
    f16* pw2   = pw1at + 16384;

    prep_kernel<<<280, 256, 0, stream>>>(W1, W2, state, b1, pw1at, pw2, hstate);
    fused_kernel<<<2000, 256, 0, stream>>>(afeat, hstate, pw1at, pw2, b2, W3, b3, out);
}